// Round 6
// baseline (1093.425 us; speedup 1.0000x reference)
//
#include <hip/hip_runtime.h>
#include <hip/hip_bf16.h>
#include <math.h>

#define B_  4
#define S_  4096
#define D_  1024
#define H_  1536
#define M_  (B_*S_)          // 16384 rows
#define CCONST 8.0f

#define CL  128              // scan chunk length
#define NC  (S_/CL)          // 32 chunks

#define BM 128
#define BN 128
#define BK 32

using bf16x8 = __attribute__((ext_vector_type(8))) short;
using f32x4  = __attribute__((ext_vector_type(4))) float;
using u16x8  = __attribute__((ext_vector_type(8))) unsigned short;

__device__ __forceinline__ float bf2f(unsigned short u){
    union{unsigned i; float f;} v; v.i = ((unsigned)u)<<16; return v.f;
}
__device__ __forceinline__ unsigned short f2bf(float f){
    union{float f; unsigned i;} v; v.f = f;
    unsigned r = v.i + 0x7fffu + ((v.i>>16)&1u);
    return (unsigned short)(r>>16);
}

#define GLOAD16(gp, lp) __builtin_amdgcn_global_load_lds( \
    (const __attribute__((address_space(1))) void*)(gp),  \
    (__attribute__((address_space(3))) void*)(lp), 16, 0, 0)

// ---------------- cast f32 -> bf16, 8 elems/thread ----------------
__global__ void cast_bf16_kernel(const float* __restrict__ in,
                                 unsigned short* __restrict__ out, int n8)
{
    int i = blockIdx.x*blockDim.x + threadIdx.x;
    if (i >= n8) return;
    const float4* p = reinterpret_cast<const float4*>(in + (size_t)i*8);
    float4 a = p[0], b = p[1];
    u16x8 o;
    o[0]=f2bf(a.x); o[1]=f2bf(a.y); o[2]=f2bf(a.z); o[3]=f2bf(a.w);
    o[4]=f2bf(b.x); o[5]=f2bf(b.y); o[6]=f2bf(b.z); o[7]=f2bf(b.w);
    *reinterpret_cast<u16x8*>(out + (size_t)i*8) = o;
}

// ---------------- GEMM C[M,N] = A[M,K] * Bw[N,K]^T (2-phase dbuf) --------
// MODE 0: store bf16   MODE 2: store f32
template<int MODE>
__global__ __launch_bounds__(256) void gemm_bt(
    const unsigned short* __restrict__ A, const unsigned short* __restrict__ Bw,
    void* __restrict__ out, int M, int N, int K)
{
    __shared__ alignas(16) unsigned short As[2][BM*BK];
    __shared__ alignas(16) unsigned short Bs[2][BN*BK];
    const int tid = threadIdx.x, lane = tid&63, wid = tid>>6;
    const int row0 = blockIdx.x*BM, col0 = blockIdx.y*BN;
    const int wr = (wid>>1)*64, wc = (wid&1)*64;
    const int lr = lane&15, kg = lane>>4;

    // staging geometry (per wave: 2 chunks of 64 lanes x 8 elems)
    const int eb0 = (wid*64)*8,  eb1 = ((256 + wid*64))*8;
    const int le0 = eb0 + lane*8, le1 = eb1 + lane*8;
    const int ar0 = le0>>5, ac0 = le0&31;
    const int ar1 = le1>>5, ac1 = le1&31;

    auto stage = [&](int buf, int k0){
        GLOAD16(&A [(size_t)(row0+ar0)*K + (k0+ac0)], &As[buf][eb0]);
        GLOAD16(&Bw[(size_t)(col0+ar0)*K + (k0+ac0)], &Bs[buf][eb0]);
        GLOAD16(&A [(size_t)(row0+ar1)*K + (k0+ac1)], &As[buf][eb1]);
        GLOAD16(&Bw[(size_t)(col0+ar1)*K + (k0+ac1)], &Bs[buf][eb1]);
    };

    f32x4 acc[4][4];
    #pragma unroll
    for (int m=0;m<4;m++)
        #pragma unroll
        for (int n=0;n<4;n++) acc[m][n] = (f32x4){0.f,0.f,0.f,0.f};

    const int nk = K/BK;
    stage(0, 0);
    __syncthreads();            // drain prologue loads
    int cur = 0;
    for (int t=0; t<nk; ++t){
        if (t+1 < nk) stage(cur^1, (t+1)*BK);   // issue next-tile loads FIRST
        bf16x8 af[4], bfr[4];
        #pragma unroll
        for (int m=0;m<4;m++) af[m]  = *(const bf16x8*)&As[cur][(wr + m*16 + lr)*BK + kg*8];
        #pragma unroll
        for (int n=0;n<4;n++) bfr[n] = *(const bf16x8*)&Bs[cur][(wc + n*16 + lr)*BK + kg*8];
        #pragma unroll
        for (int m=0;m<4;m++)
            #pragma unroll
            for (int n=0;n<4;n++)
                acc[m][n] = __builtin_amdgcn_mfma_f32_16x16x32_bf16(af[m], bfr[n], acc[m][n], 0,0,0);
        __syncthreads();        // drains vmcnt (next loads overlapped compute) + lgkm
        cur ^= 1;
    }

    #pragma unroll
    for (int n=0;n<4;n++){
        int c = col0 + wc + n*16 + lr;
        #pragma unroll
        for (int m=0;m<4;m++){
            int rbase = row0 + wr + m*16 + kg*4;
            #pragma unroll
            for (int j=0;j<4;j++){
                float v = acc[m][n][j];
                size_t idx = (size_t)(rbase+j)*N + c;
                if constexpr (MODE==0){
                    ((unsigned short*)out)[idx] = f2bf(v);
                } else {
                    ((float*)out)[idx] = v;
                }
            }
        }
    }
}

// ---------------- dual GEMM skeleton: C1 = A*B1^T, C2 = A*B2^T ------------
// EPI 0: gate/u epilogue  (gelu(z1)->O1 bf16, z2->O2 bf16)
// EPI 1: RG-LRU epilogue  (la bf16 -> O1, xbeta bf16 -> O2; reads Yb=A, biases)
template<int EPI>
__global__ __launch_bounds__(256) void gemm_dual(
    const unsigned short* __restrict__ Aall,
    const unsigned short* __restrict__ B1, const unsigned short* __restrict__ B2,
    unsigned short* __restrict__ O1, unsigned short* __restrict__ O2,
    const float* __restrict__ bi, const float* __restrict__ bg,
    const float* __restrict__ lam,
    int N, int K)
{
    __shared__ alignas(16) unsigned short As [2][BM*BK];
    __shared__ alignas(16) unsigned short Bs1[2][BN*BK];
    __shared__ alignas(16) unsigned short Bs2[2][BN*BK];
    const int tid = threadIdx.x, lane = tid&63, wid = tid>>6;
    const int row0 = blockIdx.x*BM, col0 = blockIdx.y*BN;
    const int wr = (wid>>1)*64, wc = (wid&1)*64;
    const int lr = lane&15, kg = lane>>4;

    const int eb0 = (wid*64)*8,  eb1 = ((256 + wid*64))*8;
    const int le0 = eb0 + lane*8, le1 = eb1 + lane*8;
    const int ar0 = le0>>5, ac0 = le0&31;
    const int ar1 = le1>>5, ac1 = le1&31;

    auto stage = [&](int buf, int k0){
        GLOAD16(&Aall[(size_t)(row0+ar0)*K + (k0+ac0)], &As [buf][eb0]);
        GLOAD16(&B1  [(size_t)(col0+ar0)*K + (k0+ac0)], &Bs1[buf][eb0]);
        GLOAD16(&B2  [(size_t)(col0+ar0)*K + (k0+ac0)], &Bs2[buf][eb0]);
        GLOAD16(&Aall[(size_t)(row0+ar1)*K + (k0+ac1)], &As [buf][eb1]);
        GLOAD16(&B1  [(size_t)(col0+ar1)*K + (k0+ac1)], &Bs1[buf][eb1]);
        GLOAD16(&B2  [(size_t)(col0+ar1)*K + (k0+ac1)], &Bs2[buf][eb1]);
    };

    f32x4 a1[4][4], a2[4][4];
    #pragma unroll
    for (int m=0;m<4;m++)
        #pragma unroll
        for (int n=0;n<4;n++){ a1[m][n]=(f32x4){0.f,0.f,0.f,0.f}; a2[m][n]=(f32x4){0.f,0.f,0.f,0.f}; }

    const int nk = K/BK;
    stage(0, 0);
    __syncthreads();
    int cur = 0;
    for (int t=0; t<nk; ++t){
        if (t+1 < nk) stage(cur^1, (t+1)*BK);
        bf16x8 af[4], b1f[4], b2f[4];
        #pragma unroll
        for (int m=0;m<4;m++) af[m]  = *(const bf16x8*)&As [cur][(wr + m*16 + lr)*BK + kg*8];
        #pragma unroll
        for (int n=0;n<4;n++){ b1f[n] = *(const bf16x8*)&Bs1[cur][(wc + n*16 + lr)*BK + kg*8];
                               b2f[n] = *(const bf16x8*)&Bs2[cur][(wc + n*16 + lr)*BK + kg*8]; }
        #pragma unroll
        for (int m=0;m<4;m++)
            #pragma unroll
            for (int n=0;n<4;n++){
                a1[m][n] = __builtin_amdgcn_mfma_f32_16x16x32_bf16(af[m], b1f[n], a1[m][n], 0,0,0);
                a2[m][n] = __builtin_amdgcn_mfma_f32_16x16x32_bf16(af[m], b2f[n], a2[m][n], 0,0,0);
            }
        __syncthreads();
        cur ^= 1;
    }

    #pragma unroll
    for (int n=0;n<4;n++){
        int c = col0 + wc + n*16 + lr;
        float bic = 0.f, msp = 0.f, bgc = 0.f;
        if constexpr (EPI==1){
            bic = bi[c]; bgc = bg[c];
            msp = -CCONST * log1pf(expf(lam[c]));   // -C*softplus(lam)
        }
        #pragma unroll
        for (int m=0;m<4;m++){
            int rbase = row0 + wr + m*16 + kg*4;
            #pragma unroll
            for (int j=0;j<4;j++){
                size_t idx = (size_t)(rbase+j)*N + c;
                float z1 = a1[m][n][j];
                float z2 = a2[m][n][j];
                if constexpr (EPI==0){
                    // O1 = gelu(z1) [gate], O2 = z2 [u]
                    float g = 0.5f*z1*(1.0f + erff(z1*0.70710678118654752f));
                    O1[idx] = f2bf(g);
                    O2[idx] = f2bf(z2);
                } else {
                    // z1 -> ig, z2 -> rg
                    float zi = z1 + bic;
                    float zg = z2 + bgc;
                    float ig = 1.f/(1.f+expf(-zi));
                    float rg = 1.f/(1.f+expf(-zg));
                    float lav = msp*rg;               // log(alpha) in [-0.106, 0]
                    float a  = expf(lav);
                    float bt = sqrtf(1.f - a*a + 1e-6f);
                    float y  = bf2f(Aall[idx]);       // N == K here (H_), A is Y
                    O1[idx] = f2bf(lav);
                    O2[idx] = f2bf(bt*ig*y);
                }
            }
        }
    }
}

// ---------------- causal depthwise conv1d (K=4), bf16 in/out ----------------
__global__ void conv_kernel(const unsigned short* __restrict__ U,
                            const float* __restrict__ W,  // [H,1,4]
                            const float* __restrict__ Cb, // [H]
                            unsigned short* __restrict__ Y)
{
    int gid = blockIdx.x*blockDim.x + threadIdx.x;   // over M_*H_/8
    int hc = gid % (H_/8); int m = gid / (H_/8);
    int s = m & (S_-1);
    int h0 = hc*8;
    size_t base = (size_t)m*H_ + h0;
    float acc[8];
    #pragma unroll
    for (int j=0;j<8;j++) acc[j] = Cb[h0+j];
    #pragma unroll
    for (int i=0;i<4;i++){
        int ss = s - 3 + i;
        if (ss < 0) continue;
        u16x8 uv = *reinterpret_cast<const u16x8*>(&U[(size_t)(m-3+i)*H_ + h0]);
        #pragma unroll
        for (int j=0;j<8;j++) acc[j] += W[(h0+j)*4 + i] * bf2f(uv[j]);
    }
    u16x8 o;
    #pragma unroll
    for (int j=0;j<8;j++) o[j] = f2bf(acc[j]);
    *reinterpret_cast<u16x8*>(&Y[base]) = o;
}

// ---------------- scan phase 1: per-chunk affine summary ----------------
__global__ void scan1_kernel(const unsigned short* __restrict__ la,
                             const unsigned short* __restrict__ xbeta,
                             float* __restrict__ Ac, float* __restrict__ Bc)
{
    int h = blockIdx.x*blockDim.x + threadIdx.x;   // 0..H_
    int b = blockIdx.y, c = blockIdx.z;
    size_t base = ((size_t)b*S_ + (size_t)c*CL)*H_ + h;
    float sa = 0.f, Bv = 0.f;
    for (int t=0;t<CL;t++){
        float l = bf2f(la   [base + (size_t)t*H_]);
        float x = bf2f(xbeta[base + (size_t)t*H_]);
        Bv = expf(l)*Bv + x;
        sa += l;
    }
    size_t o = ((size_t)c*B_ + b)*H_ + h;
    Ac[o] = expf(sa); Bc[o] = Bv;
}

// ---------------- scan phase 2: sequential over chunk states ----------------
__global__ void scan2_kernel(const float* __restrict__ Ac, const float* __restrict__ Bc,
                             float* __restrict__ Hin)
{
    int idx = blockIdx.x*blockDim.x + threadIdx.x;  // over B_*H_
    int b = idx / H_, h = idx % H_;
    float hcur = 0.f;
    for (int c=0;c<NC;c++){
        size_t o = ((size_t)c*B_ + b)*H_ + h;
        Hin[o] = hcur;
        hcur = Ac[o]*hcur + Bc[o];
    }
}

// ---------------- scan phase 3: replay + gelu(gate)*h -> bf16 ----------------
__global__ void scan3_kernel(const unsigned short* __restrict__ la,
                             const unsigned short* __restrict__ xbeta,
                             const float* __restrict__ Hin,
                             const unsigned short* __restrict__ Gg,
                             unsigned short* __restrict__ Vb)
{
    int h = blockIdx.x*blockDim.x + threadIdx.x;
    int b = blockIdx.y, c = blockIdx.z;
    size_t base = ((size_t)b*S_ + (size_t)c*CL)*H_ + h;
    float hcur = Hin[((size_t)c*B_ + b)*H_ + h];
    for (int t=0;t<CL;t++){
        size_t o = base + (size_t)t*H_;
        float l = bf2f(la[o]);
        float x = bf2f(xbeta[o]);
        hcur = expf(l)*hcur + x;
        float g = bf2f(Gg[o]);
        Vb[o] = f2bf(g*hcur);
    }
}

extern "C" void kernel_launch(void* const* d_in, const int* in_sizes, int n_in,
                              void* d_out, int out_size, void* d_ws, size_t ws_size,
                              hipStream_t stream)
{
    const float* x      = (const float*)d_in[0];
    const float* Wg     = (const float*)d_in[1];
    const float* Wi     = (const float*)d_in[2];
    const float* conv_w = (const float*)d_in[3];
    const float* conv_b = (const float*)d_in[4];
    const float* lru_Wi = (const float*)d_in[5];
    const float* lru_bi = (const float*)d_in[6];
    const float* lru_Wg = (const float*)d_in[7];
    const float* lru_bg = (const float*)d_in[8];
    const float* lam    = (const float*)d_in[9];
    const float* Wo     = (const float*)d_in[10];
    float* out = (float*)d_out;

    // ---- workspace arena (~212 MB) ----
    const size_t BY16 = (size_t)M_*H_*2;   // 48 MiB bf16 [M,H] buffer
    char* w = (char*)d_ws;
    // R0: xb (steps 1-3) then la (steps 5-8) — lifetimes disjoint
    unsigned short* xb    = (unsigned short*)w;
    unsigned short* la    = (unsigned short*)w;  w += BY16;
    unsigned short* ggb   = (unsigned short*)w;  w += BY16;   // gate (gelu'd)
    unsigned short* ub    = (unsigned short*)w;  w += BY16;   // u, later v
    unsigned short* xbeta = (unsigned short*)w;  w += BY16;
    unsigned short* wgb   = (unsigned short*)w;  w += (size_t)H_*D_*2;
    unsigned short* wib   = (unsigned short*)w;  w += (size_t)H_*D_*2;
    unsigned short* wliB  = (unsigned short*)w;  w += (size_t)H_*H_*2;
    unsigned short* wlgB  = (unsigned short*)w;  w += (size_t)H_*H_*2;
    unsigned short* wob   = (unsigned short*)w;  w += (size_t)D_*H_*2;
    float* Ac  = (float*)w; w += (size_t)NC*B_*H_*4;
    float* Bc  = (float*)w; w += (size_t)NC*B_*H_*4;
    float* Hin = (float*)w; w += (size_t)NC*B_*H_*4;
    // yb lives inside d_out (48 MiB of its 64 MiB), dead before final GEMM
    unsigned short* yb = (unsigned short*)d_out;
    unsigned short* vb = ub;

    size_t need = (size_t)(w - (char*)d_ws);
    if (ws_size < need) return;   // diagnostic guard

    // casts to bf16
    cast_bf16_kernel<<<(M_*D_/8)/256,   256, 0, stream>>>(x,      xb,   M_*D_/8);
    cast_bf16_kernel<<<(H_*D_/8)/256,   256, 0, stream>>>(Wg,     wgb,  H_*D_/8);
    cast_bf16_kernel<<<(H_*D_/8)/256,   256, 0, stream>>>(Wi,     wib,  H_*D_/8);
    cast_bf16_kernel<<<(H_*H_/8)/256,   256, 0, stream>>>(lru_Wi, wliB, H_*H_/8);
    cast_bf16_kernel<<<(H_*H_/8)/256,   256, 0, stream>>>(lru_Wg, wlgB, H_*H_/8);
    cast_bf16_kernel<<<(D_*H_/8)/256,   256, 0, stream>>>(Wo,     wob,  D_*H_/8);

    // fused: gate = gelu(x Wg^T), u = x Wi^T  (one dual-B GEMM)
    gemm_dual<0><<<dim3(M_/BM, H_/BN), 256, 0, stream>>>(
        xb, wgb, wib, ggb, ub, nullptr, nullptr, nullptr, H_, D_);

    // causal depthwise conv
    conv_kernel<<<(M_*(H_/8))/256, 256, 0, stream>>>(ub, conv_w, conv_b, yb);

    // RG-LRU gates -> la (log-alpha) + xbeta, fused dual GEMM
    gemm_dual<1><<<dim3(M_/BM, H_/BN), 256, 0, stream>>>(
        yb, wliB, wlgB, la, xbeta, lru_bi, lru_bg, lam, H_, H_);

    // chunked linear recurrence
    scan1_kernel<<<dim3(H_/256, B_, NC), 256, 0, stream>>>(la, xbeta, Ac, Bc);
    scan2_kernel<<<(B_*H_)/256, 256, 0, stream>>>(Ac, Bc, Hin);
    scan3_kernel<<<dim3(H_/256, B_, NC), 256, 0, stream>>>(la, xbeta, Hin, ggb, vb);

    // out = (gelu(gate) * h) Wo^T  (yb region of d_out is dead by now)
    gemm_bt<2><<<dim3(M_/BM, D_/BN), 256, 0, stream>>>(vb, wob, out, M_, D_, H_);
}

// Round 7
// 957.163 us; speedup vs baseline: 1.1424x; 1.1424x over previous
//
#include <hip/hip_runtime.h>
#include <hip/hip_bf16.h>
#include <math.h>

#define B_  4
#define S_  4096
#define D_  1024
#define H_  1536
#define M_  (B_*S_)          // 16384 rows
#define CCONST 8.0f

#define CL  128              // scan chunk length
#define NC  (S_/CL)          // 32 chunks

#define BM 128
#define BN 128
#define BK 32

using bf16x8 = __attribute__((ext_vector_type(8))) short;
using f32x4  = __attribute__((ext_vector_type(4))) float;
using u16x8  = __attribute__((ext_vector_type(8))) unsigned short;

__device__ __forceinline__ float bf2f(unsigned short u){
    union{unsigned i; float f;} v; v.i = ((unsigned)u)<<16; return v.f;
}
__device__ __forceinline__ unsigned short f2bf(float f){
    union{float f; unsigned i;} v; v.f = f;
    unsigned r = v.i + 0x7fffu + ((v.i>>16)&1u);
    return (unsigned short)(r>>16);
}

#define GLOAD16(gp, lp) __builtin_amdgcn_global_load_lds( \
    (const __attribute__((address_space(1))) void*)(gp),  \
    (__attribute__((address_space(3))) void*)(lp), 16, 0, 0)

// counted-vmcnt barrier: my ds_reads done (lgkm 0), all but NEWEST 'n' vmem retired
#define WAITBAR(vm_asm)                                   \
    do {                                                  \
        asm volatile(vm_asm ::: "memory");                \
        __builtin_amdgcn_sched_barrier(0);                \
        __builtin_amdgcn_s_barrier();                     \
        __builtin_amdgcn_sched_barrier(0);                \
    } while (0)

// ---------------- cast f32 -> bf16, 8 elems/thread ----------------
__global__ void cast_bf16_kernel(const float* __restrict__ in,
                                 unsigned short* __restrict__ out, int n8)
{
    int i = blockIdx.x*blockDim.x + threadIdx.x;
    if (i >= n8) return;
    const float4* p = reinterpret_cast<const float4*>(in + (size_t)i*8);
    float4 a = p[0], b = p[1];
    u16x8 o;
    o[0]=f2bf(a.x); o[1]=f2bf(a.y); o[2]=f2bf(a.z); o[3]=f2bf(a.w);
    o[4]=f2bf(b.x); o[5]=f2bf(b.y); o[6]=f2bf(b.z); o[7]=f2bf(b.w);
    *reinterpret_cast<u16x8*>(out + (size_t)i*8) = o;
}

// ---------------- GEMM C[M,N] = A[M,K] * Bw[N,K]^T (3-buf counted-vmcnt) --
// MODE 0: store bf16   MODE 2: store f32
template<int MODE>
__global__ __launch_bounds__(256) void gemm_bt(
    const unsigned short* __restrict__ A, const unsigned short* __restrict__ Bw,
    void* __restrict__ out, int M, int N, int K)
{
    __shared__ alignas(16) unsigned short As[3][BM*BK];
    __shared__ alignas(16) unsigned short Bs[3][BN*BK];
    const int tid = threadIdx.x, lane = tid&63, wid = tid>>6;
    const int row0 = blockIdx.x*BM, col0 = blockIdx.y*BN;
    const int wr = (wid>>1)*64, wc = (wid&1)*64;
    const int lr = lane&15, kg = lane>>4;

    const int eb0 = (wid*64)*8,  eb1 = ((256 + wid*64))*8;
    const int le0 = eb0 + lane*8, le1 = eb1 + lane*8;
    const int ar0 = le0>>5, ac0 = le0&31;
    const int ar1 = le1>>5, ac1 = le1&31;

    auto stage = [&](int buf, int k0){   // 4 loads per thread-batch
        GLOAD16(&A [(size_t)(row0+ar0)*K + (k0+ac0)], &As[buf][eb0]);
        GLOAD16(&Bw[(size_t)(col0+ar0)*K + (k0+ac0)], &Bs[buf][eb0]);
        GLOAD16(&A [(size_t)(row0+ar1)*K + (k0+ac1)], &As[buf][eb1]);
        GLOAD16(&Bw[(size_t)(col0+ar1)*K + (k0+ac1)], &Bs[buf][eb1]);
    };

    f32x4 acc[4][4];
    #pragma unroll
    for (int m=0;m<4;m++)
        #pragma unroll
        for (int n=0;n<4;n++) acc[m][n] = (f32x4){0.f,0.f,0.f,0.f};

    const int nk = K/BK;                 // >= 32 for all our shapes
    stage(0, 0);
    stage(1, BK);
    // batch0 landed (4 newest = batch1 may be in flight), all waves synced
    WAITBAR("s_waitcnt vmcnt(4)");
    int cur = 0;
    for (int t=0; t<nk; ++t){
        bf16x8 af[4], bfr[4];
        #pragma unroll
        for (int m=0;m<4;m++) af[m]  = *(const bf16x8*)&As[cur][(wr + m*16 + lr)*BK + kg*8];
        #pragma unroll
        for (int n=0;n<4;n++) bfr[n] = *(const bf16x8*)&Bs[cur][(wc + n*16 + lr)*BK + kg*8];
        int nxt = cur+1==3 ? 0 : cur+1;
        int nnx = nxt+1==3 ? 0 : nxt+1;
        if (t+2 < nk){
            stage(nnx, (t+2)*BK);
            WAITBAR("s_waitcnt vmcnt(4) lgkmcnt(0)");   // batch t+1 landed; t+2 in flight
        } else {
            WAITBAR("s_waitcnt vmcnt(0) lgkmcnt(0)");   // tail: drain
        }
        #pragma unroll
        for (int m=0;m<4;m++)
            #pragma unroll
            for (int n=0;n<4;n++)
                acc[m][n] = __builtin_amdgcn_mfma_f32_16x16x32_bf16(af[m], bfr[n], acc[m][n], 0,0,0);
        cur = nxt;
    }

    #pragma unroll
    for (int n=0;n<4;n++){
        int c = col0 + wc + n*16 + lr;
        #pragma unroll
        for (int m=0;m<4;m++){
            int rbase = row0 + wr + m*16 + kg*4;
            #pragma unroll
            for (int j=0;j<4;j++){
                float v = acc[m][n][j];
                size_t idx = (size_t)(rbase+j)*N + c;
                if constexpr (MODE==0){
                    ((unsigned short*)out)[idx] = f2bf(v);
                } else {
                    ((float*)out)[idx] = v;
                }
            }
        }
    }
}

// ---------------- dual GEMM skeleton: C1 = A*B1^T, C2 = A*B2^T ------------
// EPI 0: gate/u epilogue  (gelu(z1)->O1 bf16, z2->O2 bf16)
// EPI 1: RG-LRU epilogue  (la bf16 -> O1, xbeta bf16 -> O2; reads Yb=A, biases)
template<int EPI>
__global__ __launch_bounds__(256) void gemm_dual(
    const unsigned short* __restrict__ Aall,
    const unsigned short* __restrict__ B1, const unsigned short* __restrict__ B2,
    unsigned short* __restrict__ O1, unsigned short* __restrict__ O2,
    const float* __restrict__ bi, const float* __restrict__ bg,
    const float* __restrict__ lam,
    int N, int K)
{
    __shared__ alignas(16) unsigned short As [3][BM*BK];
    __shared__ alignas(16) unsigned short Bs1[3][BN*BK];
    __shared__ alignas(16) unsigned short Bs2[3][BN*BK];
    const int tid = threadIdx.x, lane = tid&63, wid = tid>>6;
    const int row0 = blockIdx.x*BM, col0 = blockIdx.y*BN;
    const int wr = (wid>>1)*64, wc = (wid&1)*64;
    const int lr = lane&15, kg = lane>>4;

    const int eb0 = (wid*64)*8,  eb1 = ((256 + wid*64))*8;
    const int le0 = eb0 + lane*8, le1 = eb1 + lane*8;
    const int ar0 = le0>>5, ac0 = le0&31;
    const int ar1 = le1>>5, ac1 = le1&31;

    auto stage = [&](int buf, int k0){   // 6 loads per thread-batch
        GLOAD16(&Aall[(size_t)(row0+ar0)*K + (k0+ac0)], &As [buf][eb0]);
        GLOAD16(&B1  [(size_t)(col0+ar0)*K + (k0+ac0)], &Bs1[buf][eb0]);
        GLOAD16(&B2  [(size_t)(col0+ar0)*K + (k0+ac0)], &Bs2[buf][eb0]);
        GLOAD16(&Aall[(size_t)(row0+ar1)*K + (k0+ac1)], &As [buf][eb1]);
        GLOAD16(&B1  [(size_t)(col0+ar1)*K + (k0+ac1)], &Bs1[buf][eb1]);
        GLOAD16(&B2  [(size_t)(col0+ar1)*K + (k0+ac1)], &Bs2[buf][eb1]);
    };

    f32x4 a1[4][4], a2[4][4];
    #pragma unroll
    for (int m=0;m<4;m++)
        #pragma unroll
        for (int n=0;n<4;n++){ a1[m][n]=(f32x4){0.f,0.f,0.f,0.f}; a2[m][n]=(f32x4){0.f,0.f,0.f,0.f}; }

    const int nk = K/BK;
    stage(0, 0);
    stage(1, BK);
    WAITBAR("s_waitcnt vmcnt(6)");       // batch0 landed; batch1 in flight
    int cur = 0;
    for (int t=0; t<nk; ++t){
        bf16x8 af[4], b1f[4], b2f[4];
        #pragma unroll
        for (int m=0;m<4;m++) af[m]  = *(const bf16x8*)&As [cur][(wr + m*16 + lr)*BK + kg*8];
        #pragma unroll
        for (int n=0;n<4;n++){ b1f[n] = *(const bf16x8*)&Bs1[cur][(wc + n*16 + lr)*BK + kg*8];
                               b2f[n] = *(const bf16x8*)&Bs2[cur][(wc + n*16 + lr)*BK + kg*8]; }
        int nxt = cur+1==3 ? 0 : cur+1;
        int nnx = nxt+1==3 ? 0 : nxt+1;
        if (t+2 < nk){
            stage(nnx, (t+2)*BK);
            WAITBAR("s_waitcnt vmcnt(6) lgkmcnt(0)");   // batch t+1 landed; t+2 in flight
        } else {
            WAITBAR("s_waitcnt vmcnt(0) lgkmcnt(0)");
        }
        #pragma unroll
        for (int m=0;m<4;m++)
            #pragma unroll
            for (int n=0;n<4;n++){
                a1[m][n] = __builtin_amdgcn_mfma_f32_16x16x32_bf16(af[m], b1f[n], a1[m][n], 0,0,0);
                a2[m][n] = __builtin_amdgcn_mfma_f32_16x16x32_bf16(af[m], b2f[n], a2[m][n], 0,0,0);
            }
        cur = nxt;
    }

    #pragma unroll
    for (int n=0;n<4;n++){
        int c = col0 + wc + n*16 + lr;
        float bic = 0.f, msp = 0.f, bgc = 0.f;
        if constexpr (EPI==1){
            bic = bi[c]; bgc = bg[c];
            msp = -CCONST * log1pf(expf(lam[c]));   // -C*softplus(lam)
        }
        #pragma unroll
        for (int m=0;m<4;m++){
            int rbase = row0 + wr + m*16 + kg*4;
            #pragma unroll
            for (int j=0;j<4;j++){
                size_t idx = (size_t)(rbase+j)*N + c;
                float z1 = a1[m][n][j];
                float z2 = a2[m][n][j];
                if constexpr (EPI==0){
                    float g = 0.5f*z1*(1.0f + erff(z1*0.70710678118654752f));
                    O1[idx] = f2bf(g);
                    O2[idx] = f2bf(z2);
                } else {
                    float zi = z1 + bic;
                    float zg = z2 + bgc;
                    float ig = 1.f/(1.f+expf(-zi));
                    float rg = 1.f/(1.f+expf(-zg));
                    float lav = msp*rg;               // log(alpha) in [-0.106, 0]
                    float a  = expf(lav);
                    float bt = sqrtf(1.f - a*a + 1e-6f);
                    float y  = bf2f(Aall[idx]);       // N == K here (H_), A is Y
                    O1[idx] = f2bf(lav);
                    O2[idx] = f2bf(bt*ig*y);
                }
            }
        }
    }
}

// ---------------- causal depthwise conv1d (K=4), bf16 in/out ----------------
__global__ void conv_kernel(const unsigned short* __restrict__ U,
                            const float* __restrict__ W,  // [H,1,4]
                            const float* __restrict__ Cb, // [H]
                            unsigned short* __restrict__ Y)
{
    int gid = blockIdx.x*blockDim.x + threadIdx.x;   // over M_*H_/8
    int hc = gid % (H_/8); int m = gid / (H_/8);
    int s = m & (S_-1);
    int h0 = hc*8;
    size_t base = (size_t)m*H_ + h0;
    float acc[8];
    #pragma unroll
    for (int j=0;j<8;j++) acc[j] = Cb[h0+j];
    #pragma unroll
    for (int i=0;i<4;i++){
        int ss = s - 3 + i;
        if (ss < 0) continue;
        u16x8 uv = *reinterpret_cast<const u16x8*>(&U[(size_t)(m-3+i)*H_ + h0]);
        #pragma unroll
        for (int j=0;j<8;j++) acc[j] += W[(h0+j)*4 + i] * bf2f(uv[j]);
    }
    u16x8 o;
    #pragma unroll
    for (int j=0;j<8;j++) o[j] = f2bf(acc[j]);
    *reinterpret_cast<u16x8*>(&Y[base]) = o;
}

// ---------------- scan phase 1: per-chunk affine summary ----------------
__global__ void scan1_kernel(const unsigned short* __restrict__ la,
                             const unsigned short* __restrict__ xbeta,
                             float* __restrict__ Ac, float* __restrict__ Bc)
{
    int h = blockIdx.x*blockDim.x + threadIdx.x;   // 0..H_
    int b = blockIdx.y, c = blockIdx.z;
    size_t base = ((size_t)b*S_ + (size_t)c*CL)*H_ + h;
    float sa = 0.f, Bv = 0.f;
    for (int t=0;t<CL;t++){
        float l = bf2f(la   [base + (size_t)t*H_]);
        float x = bf2f(xbeta[base + (size_t)t*H_]);
        Bv = expf(l)*Bv + x;
        sa += l;
    }
    size_t o = ((size_t)c*B_ + b)*H_ + h;
    Ac[o] = expf(sa); Bc[o] = Bv;
}

// ---------------- scan phase 2: sequential over chunk states ----------------
__global__ void scan2_kernel(const float* __restrict__ Ac, const float* __restrict__ Bc,
                             float* __restrict__ Hin)
{
    int idx = blockIdx.x*blockDim.x + threadIdx.x;  // over B_*H_
    int b = idx / H_, h = idx % H_;
    float hcur = 0.f;
    for (int c=0;c<NC;c++){
        size_t o = ((size_t)c*B_ + b)*H_ + h;
        Hin[o] = hcur;
        hcur = Ac[o]*hcur + Bc[o];
    }
}

// ---------------- scan phase 3: replay + gelu(gate)*h -> bf16 ----------------
__global__ void scan3_kernel(const unsigned short* __restrict__ la,
                             const unsigned short* __restrict__ xbeta,
                             const float* __restrict__ Hin,
                             const unsigned short* __restrict__ Gg,
                             unsigned short* __restrict__ Vb)
{
    int h = blockIdx.x*blockDim.x + threadIdx.x;
    int b = blockIdx.y, c = blockIdx.z;
    size_t base = ((size_t)b*S_ + (size_t)c*CL)*H_ + h;
    float hcur = Hin[((size_t)c*B_ + b)*H_ + h];
    for (int t=0;t<CL;t++){
        size_t o = base + (size_t)t*H_;
        float l = bf2f(la[o]);
        float x = bf2f(xbeta[o]);
        hcur = expf(l)*hcur + x;
        float g = bf2f(Gg[o]);
        Vb[o] = f2bf(g*hcur);
    }
}

extern "C" void kernel_launch(void* const* d_in, const int* in_sizes, int n_in,
                              void* d_out, int out_size, void* d_ws, size_t ws_size,
                              hipStream_t stream)
{
    const float* x      = (const float*)d_in[0];
    const float* Wg     = (const float*)d_in[1];
    const float* Wi     = (const float*)d_in[2];
    const float* conv_w = (const float*)d_in[3];
    const float* conv_b = (const float*)d_in[4];
    const float* lru_Wi = (const float*)d_in[5];
    const float* lru_bi = (const float*)d_in[6];
    const float* lru_Wg = (const float*)d_in[7];
    const float* lru_bg = (const float*)d_in[8];
    const float* lam    = (const float*)d_in[9];
    const float* Wo     = (const float*)d_in[10];
    float* out = (float*)d_out;

    // ---- workspace arena (~212 MB) ----
    const size_t BY16 = (size_t)M_*H_*2;   // 48 MiB bf16 [M,H] buffer
    char* w = (char*)d_ws;
    // R0: xb (steps 1-3) then la (steps 5-8) — lifetimes disjoint
    unsigned short* xb    = (unsigned short*)w;
    unsigned short* la    = (unsigned short*)w;  w += BY16;
    unsigned short* ggb   = (unsigned short*)w;  w += BY16;   // gate (gelu'd)
    unsigned short* ub    = (unsigned short*)w;  w += BY16;   // u, later v
    unsigned short* xbeta = (unsigned short*)w;  w += BY16;
    unsigned short* wgb   = (unsigned short*)w;  w += (size_t)H_*D_*2;
    unsigned short* wib   = (unsigned short*)w;  w += (size_t)H_*D_*2;
    unsigned short* wliB  = (unsigned short*)w;  w += (size_t)H_*H_*2;
    unsigned short* wlgB  = (unsigned short*)w;  w += (size_t)H_*H_*2;
    unsigned short* wob   = (unsigned short*)w;  w += (size_t)D_*H_*2;
    float* Ac  = (float*)w; w += (size_t)NC*B_*H_*4;
    float* Bc  = (float*)w; w += (size_t)NC*B_*H_*4;
    float* Hin = (float*)w; w += (size_t)NC*B_*H_*4;
    // yb lives inside d_out (48 MiB of its 64 MiB), dead before final GEMM
    unsigned short* yb = (unsigned short*)d_out;
    unsigned short* vb = ub;

    size_t need = (size_t)(w - (char*)d_ws);
    if (ws_size < need) return;   // diagnostic guard

    // casts to bf16
    cast_bf16_kernel<<<(M_*D_/8)/256,   256, 0, stream>>>(x,      xb,   M_*D_/8);
    cast_bf16_kernel<<<(H_*D_/8)/256,   256, 0, stream>>>(Wg,     wgb,  H_*D_/8);
    cast_bf16_kernel<<<(H_*D_/8)/256,   256, 0, stream>>>(Wi,     wib,  H_*D_/8);
    cast_bf16_kernel<<<(H_*H_/8)/256,   256, 0, stream>>>(lru_Wi, wliB, H_*H_/8);
    cast_bf16_kernel<<<(H_*H_/8)/256,   256, 0, stream>>>(lru_Wg, wlgB, H_*H_/8);
    cast_bf16_kernel<<<(D_*H_/8)/256,   256, 0, stream>>>(Wo,     wob,  D_*H_/8);

    // fused: gate = gelu(x Wg^T), u = x Wi^T  (one dual-B GEMM)
    gemm_dual<0><<<dim3(M_/BM, H_/BN), 256, 0, stream>>>(
        xb, wgb, wib, ggb, ub, nullptr, nullptr, nullptr, H_, D_);

    // causal depthwise conv
    conv_kernel<<<(M_*(H_/8))/256, 256, 0, stream>>>(ub, conv_w, conv_b, yb);

    // RG-LRU gates -> la (log-alpha) + xbeta, fused dual GEMM
    gemm_dual<1><<<dim3(M_/BM, H_/BN), 256, 0, stream>>>(
        yb, wliB, wlgB, la, xbeta, lru_bi, lru_bg, lam, H_, H_);

    // chunked linear recurrence
    scan1_kernel<<<dim3(H_/256, B_, NC), 256, 0, stream>>>(la, xbeta, Ac, Bc);
    scan2_kernel<<<(B_*H_)/256, 256, 0, stream>>>(Ac, Bc, Hin);
    scan3_kernel<<<dim3(H_/256, B_, NC), 256, 0, stream>>>(la, xbeta, Hin, ggb, vb);

    // out = (gelu(gate) * h) Wo^T  (yb region of d_out is dead by now)
    gemm_bt<2><<<dim3(M_/BM, D_/BN), 256, 0, stream>>>(vb, wob, out, M_, D_, H_);
}